// Round 3
// baseline (1254.683 us; speedup 1.0000x reference)
//
#include <hip/hip_runtime.h>
#include <math.h>

// VQ-VAE quantizer: N=16384 pixels, D=256, K=8192 codes.
// d_out (float32) layout: [0]=loss, [1..4194304]=z_q_x (B,C,H,W),
// [4194305]=perplexity, [4194306..+16384]=idx (as float).
//
// The np reference computes dist = f32(f32(sx2+se2) - f32(2*sgemm)) and takes
// np.argmin (first minimum). sx2~256 makes the distances quantize to a ~3e-5
// grid -> frequent exact ties -> lowest-index tie-break decides. We replicate:
//   sx2/se2: numpy pairwise summation (two 128-blocks, 8 accumulators)
//   dot:     sequential-k fp32 FMA chain (OpenBLAS sgemm microkernel order)
//   dist:    f32(f32(sx2+se2) - 2*acc), strict-< argmin, k ascending.

#define K_EMB 8192
#define D_EMB 256
#define NPIX  16384
#define NDTOT 4194304   // NPIX * D_EMB

#define OUT_LOSS 0
#define OUT_ZQ   1
#define OUT_PERP 4194305
#define OUT_IDX  4194306

// ws layout (bytes): [0] float sse; [256] int hist[8192];
// [33024] float se2[8192]; [65792] float sx2[16384]
#define WS_HIST_OFF 256
#define WS_SE2_OFF  (256 + 32768)
#define WS_SX2_OFF  (256 + 32768 + 32768)

// ---------------------------------------------------------------------------
// sx2[n] = numpy-pairwise sum of x[n][d]^2 over d=0..255.
// numpy: 256 -> pairwise(128)+pairwise(128); each 128-block: r[0..7]=a[0..7],
// 15 strided adds, combine ((r0+r1)+(r2+r3))+((r4+r5)+(r6+r7)).
__global__ void sx2_kernel(const float* __restrict__ z,
                           float* __restrict__ sx2) {
#pragma clang fp contract(off)
    int n = blockIdx.x * 256 + threadIdx.x;
    int b = n >> 10, hw = n & 1023;
    const float* zb = z + (size_t)b * (D_EMB * 1024) + hw;
    float half[2];
#pragma unroll
    for (int h = 0; h < 2; ++h) {
        float r[8];
#pragma unroll
        for (int j = 0; j < 8; ++j) {
            float v = zb[(size_t)(h * 128 + j) * 1024];
            r[j] = v * v;           // square rounds first (contract off)
        }
        for (int i = 8; i < 128; i += 8)
#pragma unroll
            for (int j = 0; j < 8; ++j) {
                float v = zb[(size_t)(h * 128 + i + j) * 1024];
                float sq = v * v;
                r[j] = r[j] + sq;
            }
        half[h] = ((r[0] + r[1]) + (r[2] + r[3]))
                + ((r[4] + r[5]) + (r[6] + r[7]));
    }
    sx2[n] = half[0] + half[1];
}

// ---------------------------------------------------------------------------
// se2[k] = numpy-pairwise sum of emb[k][d]^2 (same tree; contiguous row).
__global__ void se2_kernel(const float* __restrict__ emb,
                           float* __restrict__ se2) {
#pragma clang fp contract(off)
    int k = blockIdx.x * 256 + threadIdx.x;
    const float* e = emb + (size_t)k * D_EMB;
    float half[2];
#pragma unroll
    for (int h = 0; h < 2; ++h) {
        float r[8];
#pragma unroll
        for (int j = 0; j < 8; ++j) {
            float v = e[h * 128 + j];
            r[j] = v * v;
        }
        for (int i = 8; i < 128; i += 8)
#pragma unroll
            for (int j = 0; j < 8; ++j) {
                float v = e[h * 128 + i + j];
                float sq = v * v;
                r[j] = r[j] + sq;
            }
        half[h] = ((r[0] + r[1]) + (r[2] + r[3]))
                + ((r[4] + r[5]) + (r[6] + r[7]));
    }
    se2[k] = half[0] + half[1];
}

// ---------------------------------------------------------------------------
// Fused distance GEMM + argmin, replicating np fp32 semantics.
// Block: 256 thr (tx=t&31, ty=t>>5). 64 pixels x all 8192 codes per block.
// Per-thread register tile: 8 px x 8 codes; d accumulated 0..255 sequentially
// with single-rounding FMA (matches OpenBLAS sgemm k-chain).
#define TN 64
#define TK 256
#define DC 32

__global__ __launch_bounds__(256) void argmin_kernel(
        const float* __restrict__ z, const float* __restrict__ emb,
        const float* __restrict__ se2, const float* __restrict__ sx2,
        float* __restrict__ out_idx) {
#pragma clang fp contract(off)
    __shared__ float Xs[DC][68];
    __shared__ float Es[DC][260];

    const int t  = threadIdx.x;
    const int tx = t & 31;
    const int ty = t >> 5;          // 0..7
    const int n0 = blockIdx.x * TN;
    const int b  = n0 >> 10;        // HW = 1024
    const int hw0 = n0 & 1023;
    const float* zb = z + (size_t)b * (D_EMB * 1024) + hw0;

    float sx2r[2][4];
#pragma unroll
    for (int g = 0; g < 2; ++g)
#pragma unroll
        for (int i = 0; i < 4; ++i)
            sx2r[g][i] = sx2[n0 + g * 32 + 4 * ty + i];

    float minv[2][4];
    int   mini[2][4];
#pragma unroll
    for (int g = 0; g < 2; ++g)
#pragma unroll
        for (int i = 0; i < 4; ++i) { minv[g][i] = 3.0e38f; mini[g][i] = 0; }

    for (int kt = 0; kt < K_EMB / TK; ++kt) {
        float acc[2][4][2][4];
#pragma unroll
        for (int pg = 0; pg < 2; ++pg)
#pragma unroll
            for (int pe = 0; pe < 4; ++pe)
#pragma unroll
                for (int cg = 0; cg < 2; ++cg)
#pragma unroll
                    for (int ce = 0; ce < 4; ++ce) acc[pg][pe][cg][ce] = 0.0f;

        for (int dc = 0; dc < D_EMB / DC; ++dc) {
            {   // stage X tile: 64 px x 32 d
                int px  = t & 63;
                int dd0 = (t >> 6) * 8;
#pragma unroll
                for (int r = 0; r < 8; ++r) {
                    int dd = dd0 + r;
                    Xs[dd][px] = zb[(size_t)(dc * DC + dd) * 1024 + px];
                }
            }
            {   // stage E tile transposed: 256 codes x 32 d
                int dd = t & 31;
                int c0 = t >> 5;
                const float* ecol = emb + (size_t)(kt * TK) * D_EMB + dc * DC + dd;
#pragma unroll
                for (int p = 0; p < 32; ++p) {
                    int c = c0 + 8 * p;
                    Es[dd][c] = ecol[(size_t)c * D_EMB];
                }
            }
            __syncthreads();
            // d ascending: global d = dc*32 + d; single FMA chain per (px,k)
#pragma unroll
            for (int d = 0; d < DC; ++d) {
                float4 xa = *(const float4*)&Xs[d][4 * ty];
                float4 xb = *(const float4*)&Xs[d][32 + 4 * ty];
                float4 ea = *(const float4*)&Es[d][4 * tx];
                float4 eb = *(const float4*)&Es[d][128 + 4 * tx];
                float xv[2][4] = {{xa.x, xa.y, xa.z, xa.w},
                                  {xb.x, xb.y, xb.z, xb.w}};
                float ev[2][4] = {{ea.x, ea.y, ea.z, ea.w},
                                  {eb.x, eb.y, eb.z, eb.w}};
#pragma unroll
                for (int pg = 0; pg < 2; ++pg)
#pragma unroll
                    for (int pe = 0; pe < 4; ++pe)
#pragma unroll
                        for (int cg = 0; cg < 2; ++cg)
#pragma unroll
                            for (int ce = 0; ce < 4; ++ce)
                                acc[pg][pe][cg][ce] = __builtin_fmaf(
                                    xv[pg][pe], ev[cg][ce],
                                    acc[pg][pe][cg][ce]);
            }
            __syncthreads();
        }
        // dist = f32(f32(sx2+se2) - 2*acc); k ascending; strict < keeps
        // the lowest index on exact fp32 ties (np.argmin first-min).
        float se2v[2][4];
#pragma unroll
        for (int cg = 0; cg < 2; ++cg)
#pragma unroll
            for (int ce = 0; ce < 4; ++ce)
                se2v[cg][ce] = se2[kt * TK + cg * 128 + 4 * tx + ce];
#pragma unroll
        for (int pg = 0; pg < 2; ++pg)
#pragma unroll
            for (int pe = 0; pe < 4; ++pe)
#pragma unroll
                for (int cg = 0; cg < 2; ++cg)
#pragma unroll
                    for (int ce = 0; ce < 4; ++ce) {
                        int k = kt * TK + cg * 128 + 4 * tx + ce;
                        float A = sx2r[pg][pe] + se2v[cg][ce];
                        float dist = A - 2.0f * acc[pg][pe][cg][ce];
                        if (dist < minv[pg][pe]) {
                            minv[pg][pe] = dist;
                            mini[pg][pe] = k;
                        }
                    }
    }

    // lexicographic (value, index) merge across the 32 tx lanes
#pragma unroll
    for (int g = 0; g < 2; ++g)
#pragma unroll
        for (int i = 0; i < 4; ++i) {
            float v = minv[g][i];
            int   ki = mini[g][i];
#pragma unroll
            for (int m = 1; m <= 16; m <<= 1) {
                float ov = __shfl_xor(v, m, 64);
                int   oi = __shfl_xor(ki, m, 64);
                if (ov < v || (ov == v && oi < ki)) { v = ov; ki = oi; }
            }
            if (tx == 0) {
                int n = n0 + g * 32 + 4 * ty + i;
                out_idx[n] = (float)ki;
            }
        }
}

// ---------------------------------------------------------------------------
// Histogram of final indices, for perplexity.
__global__ void hist_kernel(const float* __restrict__ idxf,
                            int* __restrict__ hist) {
    int n = blockIdx.x * 256 + threadIdx.x;
    atomicAdd(&hist[(int)idxf[n]], 1);
}

// ---------------------------------------------------------------------------
// Gather quantized vectors, write z_q_x, accumulate sum of squared errors.
__global__ void quantize_kernel(const float* __restrict__ z,
                                const float* __restrict__ emb,
                                const float* __restrict__ idxf,
                                float* __restrict__ zq,
                                float* __restrict__ sse) {
    int o = (blockIdx.x * 256 + threadIdx.x) * 4;
    int hw = o & 1023;
    int c  = (o >> 10) & 255;
    int b  = o >> 18;
    int nbase = b * 1024 + hw;
    float4 x = *(const float4*)(z + o);
    float q0 = emb[(size_t)((int)idxf[nbase + 0]) * D_EMB + c];
    float q1 = emb[(size_t)((int)idxf[nbase + 1]) * D_EMB + c];
    float q2 = emb[(size_t)((int)idxf[nbase + 2]) * D_EMB + c];
    float q3 = emb[(size_t)((int)idxf[nbase + 3]) * D_EMB + c];
    float4 q = make_float4(q0, q1, q2, q3);
    *(float4*)(zq + o) = q;
    float d0 = q.x - x.x, d1 = q.y - x.y, d2 = q.z - x.z, d3 = q.w - x.w;
    float s = d0 * d0 + d1 * d1 + d2 * d2 + d3 * d3;
#pragma unroll
    for (int m = 1; m < 64; m <<= 1) s += __shfl_xor(s, m, 64);
    __shared__ float red[4];
    int lane = threadIdx.x & 63, wv = threadIdx.x >> 6;
    if (lane == 0) red[wv] = s;
    __syncthreads();
    if (threadIdx.x == 0)
        atomicAdd(sse, red[0] + red[1] + red[2] + red[3]);
}

// ---------------------------------------------------------------------------
__global__ void finalize_kernel(const int* __restrict__ hist,
                                const float* __restrict__ sse,
                                float* __restrict__ out) {
    float s = 0.0f;
    for (int i = threadIdx.x; i < K_EMB; i += 256) {
        float p = (float)hist[i] * (1.0f / (float)NPIX);
        s += p * logf(p + 1e-10f);
    }
#pragma unroll
    for (int m = 1; m < 64; m <<= 1) s += __shfl_xor(s, m, 64);
    __shared__ float red[4];
    int lane = threadIdx.x & 63, wv = threadIdx.x >> 6;
    if (lane == 0) red[wv] = s;
    __syncthreads();
    if (threadIdx.x == 0) {
        float H = -(red[0] + red[1] + red[2] + red[3]);
        out[OUT_PERP] = expf(H);
        out[OUT_LOSS] = 1.25f * sse[0] / (float)NDTOT;
    }
}

// ---------------------------------------------------------------------------
extern "C" void kernel_launch(void* const* d_in, const int* in_sizes, int n_in,
                              void* d_out, int out_size, void* d_ws, size_t ws_size,
                              hipStream_t stream) {
    const float* z   = (const float*)d_in[0];   // [16,256,32,32]
    const float* emb = (const float*)d_in[1];   // [8192,256]
    float* out = (float*)d_out;
    char*  ws  = (char*)d_ws;
    float* sse  = (float*)(ws);
    int*   hist = (int*)(ws + WS_HIST_OFF);
    float* se2  = (float*)(ws + WS_SE2_OFF);
    float* sx2  = (float*)(ws + WS_SX2_OFF);

    // zero sse + hist every call (graph replays don't re-poison)
    hipMemsetAsync(d_ws, 0, WS_SE2_OFF, stream);

    sx2_kernel<<<NPIX / 256, 256, 0, stream>>>(z, sx2);
    se2_kernel<<<K_EMB / 256, 256, 0, stream>>>(emb, se2);
    argmin_kernel<<<NPIX / TN, 256, 0, stream>>>(z, emb, se2, sx2,
                                                 out + OUT_IDX);
    hist_kernel<<<NPIX / 256, 256, 0, stream>>>(out + OUT_IDX, hist);
    quantize_kernel<<<NDTOT / (256 * 4), 256, 0, stream>>>(
        z, emb, out + OUT_IDX, out + OUT_ZQ, sse);
    finalize_kernel<<<1, 256, 0, stream>>>(hist, sse, out);
}

// Round 4
// 1086.221 us; speedup vs baseline: 1.1551x; 1.1551x over previous
//
#include <hip/hip_runtime.h>
#include <math.h>

// VQ-VAE quantizer: N=16384 pixels, D=256, K=8192 codes.
// d_out (float32) layout: [0]=loss, [1..4194304]=z_q_x (B,C,H,W),
// [4194305]=perplexity, [4194306..+16384]=idx (as float).
//
// np-exact semantics (verified r3): dist = f32(f32(sx2+se2) - 2*acc) with acc
// a sequential d=0..255 fp32 FMA chain; np.argmin first-min tie-break.
// r4: persistent-X LDS + double-buffered E + 16px-x-4code thread tile ->
// FMA-bound (VALU floor 437 us).

#define K_EMB 8192
#define D_EMB 256
#define NPIX  16384
#define NDTOT 4194304   // NPIX * D_EMB

#define OUT_LOSS 0
#define OUT_ZQ   1
#define OUT_PERP 4194305
#define OUT_IDX  4194306

// ws layout (bytes): [0] float sse; [256] int hist[8192];
// [33024] float se2[8192]; [65792] float sx2[16384]
#define WS_HIST_OFF 256
#define WS_SE2_OFF  (256 + 32768)
#define WS_SX2_OFF  (256 + 32768 + 32768)

// argmin geometry
#define TN 64                 // pixels per block (grid = 256)
#define TK 256                // codes per k-tile
#define NSTEP 256             // (8192/TK) kt  x  (256/32) dc
#define XSTRIDE 68            // [256][68] floats, 16B-aligned rows
#define ESTRIDE 260           // [32][260] floats; 260%32=4 -> 2-way writes
#define EOFF (256 * XSTRIDE)  // float offset of E buffers
#define EBUF (32 * ESTRIDE)   // floats per E buffer
#define SMEM_BYTES ((EOFF + 2 * EBUF) * 4)   // 136192 B

// ---------------------------------------------------------------------------
// sx2[n] = numpy-pairwise sum of x[n][d]^2 (two 128-blocks, 8 accumulators).
__global__ void sx2_kernel(const float* __restrict__ z,
                           float* __restrict__ sx2) {
#pragma clang fp contract(off)
    int n = blockIdx.x * 256 + threadIdx.x;
    int b = n >> 10, hw = n & 1023;
    const float* zb = z + (size_t)b * (D_EMB * 1024) + hw;
    float half[2];
#pragma unroll
    for (int h = 0; h < 2; ++h) {
        float r[8];
#pragma unroll
        for (int j = 0; j < 8; ++j) {
            float v = zb[(size_t)(h * 128 + j) * 1024];
            r[j] = v * v;
        }
        for (int i = 8; i < 128; i += 8)
#pragma unroll
            for (int j = 0; j < 8; ++j) {
                float v = zb[(size_t)(h * 128 + i + j) * 1024];
                float sq = v * v;
                r[j] = r[j] + sq;
            }
        half[h] = ((r[0] + r[1]) + (r[2] + r[3]))
                + ((r[4] + r[5]) + (r[6] + r[7]));
    }
    sx2[n] = half[0] + half[1];
}

// ---------------------------------------------------------------------------
// se2[k] = numpy-pairwise sum of emb[k][d]^2.
__global__ void se2_kernel(const float* __restrict__ emb,
                           float* __restrict__ se2) {
#pragma clang fp contract(off)
    int k = blockIdx.x * 256 + threadIdx.x;
    const float* e = emb + (size_t)k * D_EMB;
    float half[2];
#pragma unroll
    for (int h = 0; h < 2; ++h) {
        float r[8];
#pragma unroll
        for (int j = 0; j < 8; ++j) {
            float v = e[h * 128 + j];
            r[j] = v * v;
        }
        for (int i = 8; i < 128; i += 8)
#pragma unroll
            for (int j = 0; j < 8; ++j) {
                float v = e[h * 128 + i + j];
                float sq = v * v;
                r[j] = r[j] + sq;
            }
        half[h] = ((r[0] + r[1]) + (r[2] + r[3]))
                + ((r[4] + r[5]) + (r[6] + r[7]));
    }
    se2[k] = half[0] + half[1];
}

// ---------------------------------------------------------------------------
// Fused distance GEMM + argmin.
// 256 thr = 4 waves; wave w owns px [16w,16w+16); lane owns codes 4*lane+ce.
// X persistent in LDS [256d][68]; E double-buffered [2][32d][260c].
__global__ __launch_bounds__(256, 1) void argmin_kernel(
        const float* __restrict__ z, const float* __restrict__ emb,
        const float* __restrict__ se2, const float* __restrict__ sx2,
        float* __restrict__ out_idx) {
#pragma clang fp contract(off)
    extern __shared__ float smem[];
    float* Xs    = smem;           // [256][XSTRIDE]
    float* Ebase = smem + EOFF;    // [2][32][ESTRIDE]

    const int t    = threadIdx.x;
    const int lane = t & 63;
    const int w    = t >> 6;
    const int n0   = blockIdx.x * TN;
    const int b    = n0 >> 10;     // HW = 1024
    const int hw0  = n0 & 1023;
    const float* zb = z + (size_t)b * (D_EMB * 1024) + hw0;

    // ---- stage X (64 px x 256 d) once: 16 float4 per thread ----
    {
        int px4 = t & 15;
        int dr  = t >> 4;
#pragma unroll
        for (int r = 0; r < 16; ++r) {
            int d = 16 * r + dr;
            float4 v = *(const float4*)(zb + (size_t)d * 1024 + 4 * px4);
            *(float4*)&Xs[d * XSTRIDE + 4 * px4] = v;
        }
    }

    // E staging mapping (per thread, 8 float4 per tile):
    //   c = w*64 + (it&3)*16 + (lane>>2)   code within tile
    //   q = (lane&3) + 4*(it>>2)           float4 d-chunk within 32 d
    //   load emb[(kt*TK + c)*256 + dc*32 + 4q], write Es[4q+j][c]
    //   -> global: 64B/4-lane coalesced; LDS write: 2 lanes/bank (free)
    const int sc = w * 64 + (lane >> 2);
    const int sq = lane & 3;

    // prologue: tile 0 (kt=0, dc=0) into buffer 0
    {
        float4 v[8];
#pragma unroll
        for (int it = 0; it < 8; ++it) {
            int c = sc + (it & 3) * 16;
            int q = sq + 4 * (it >> 2);
            v[it] = *(const float4*)(emb + (size_t)c * 256 + 4 * q);
        }
#pragma unroll
        for (int it = 0; it < 8; ++it) {
            int c = sc + (it & 3) * 16;
            int q = sq + 4 * (it >> 2);
            float* dst = Ebase + (4 * q) * ESTRIDE + c;
            dst[0 * ESTRIDE] = v[it].x;
            dst[1 * ESTRIDE] = v[it].y;
            dst[2 * ESTRIDE] = v[it].z;
            dst[3 * ESTRIDE] = v[it].w;
        }
    }
    __syncthreads();

    float sx2r[4][4];
#pragma unroll
    for (int g = 0; g < 4; ++g)
#pragma unroll
        for (int i = 0; i < 4; ++i)
            sx2r[g][i] = sx2[n0 + 16 * w + 4 * g + i];

    float minv[4][4];
    int   mini[4][4];
    float acc[4][4][4];
#pragma unroll
    for (int g = 0; g < 4; ++g)
#pragma unroll
        for (int i = 0; i < 4; ++i) {
            minv[g][i] = 3.0e38f; mini[g][i] = 0;
#pragma unroll
            for (int ce = 0; ce < 4; ++ce) acc[g][i][ce] = 0.0f;
        }

    int cur = 0;
    for (int s = 0; s < NSTEP; ++s) {
        const int dc = s & 7;
        const bool pf = (s + 1 < NSTEP);

        // T14: issue next tile's global loads before compute
        float4 v[8];
        if (pf) {
            const int kt1 = (s + 1) >> 3, dc1 = (s + 1) & 7;
#pragma unroll
            for (int it = 0; it < 8; ++it) {
                int c = sc + (it & 3) * 16;
                int q = sq + 4 * (it >> 2);
                v[it] = *(const float4*)(emb
                        + (size_t)(kt1 * TK + c) * 256 + dc1 * 32 + 4 * q);
            }
        }

        // compute: 32 d, 64 FMA each; d-chain ascending (np/BLAS order)
        const float* Ecur = Ebase + cur * EBUF;
#pragma unroll 8
        for (int d = 0; d < 32; ++d) {
            const float* xr = &Xs[(dc * 32 + d) * XSTRIDE + 16 * w];
            float4 x0 = *(const float4*)(xr + 0);
            float4 x1 = *(const float4*)(xr + 4);
            float4 x2 = *(const float4*)(xr + 8);
            float4 x3 = *(const float4*)(xr + 12);
            float4 e  = *(const float4*)&Ecur[d * ESTRIDE + 4 * lane];
            float xv[4][4] = {{x0.x, x0.y, x0.z, x0.w},
                              {x1.x, x1.y, x1.z, x1.w},
                              {x2.x, x2.y, x2.z, x2.w},
                              {x3.x, x3.y, x3.z, x3.w}};
            float ev[4] = {e.x, e.y, e.z, e.w};
#pragma unroll
            for (int g = 0; g < 4; ++g)
#pragma unroll
                for (int i = 0; i < 4; ++i)
#pragma unroll
                    for (int ce = 0; ce < 4; ++ce)
                        acc[g][i][ce] = __builtin_fmaf(
                            xv[g][i], ev[ce], acc[g][i][ce]);
        }

        // end of a k-tile: dist + argmin update, reset acc
        if ((s & 7) == 7) {
            const int kt = s >> 3;
            float4 s4 = *(const float4*)&se2[kt * TK + 4 * lane];
            float se2v[4] = {s4.x, s4.y, s4.z, s4.w};
#pragma unroll
            for (int g = 0; g < 4; ++g)
#pragma unroll
                for (int i = 0; i < 4; ++i)
#pragma unroll
                    for (int ce = 0; ce < 4; ++ce) {
                        int k = kt * TK + 4 * lane + ce;
                        float A = sx2r[g][i] + se2v[ce];
                        float dist = A - 2.0f * acc[g][i][ce];
                        if (dist < minv[g][i]) {
                            minv[g][i] = dist;
                            mini[g][i] = k;
                        }
                        acc[g][i][ce] = 0.0f;
                    }
        }

        // write prefetched tile into the other buffer
        if (pf) {
            float* Enxt = Ebase + (cur ^ 1) * EBUF;
#pragma unroll
            for (int it = 0; it < 8; ++it) {
                int c = sc + (it & 3) * 16;
                int q = sq + 4 * (it >> 2);
                float* dst = Enxt + (4 * q) * ESTRIDE + c;
                dst[0 * ESTRIDE] = v[it].x;
                dst[1 * ESTRIDE] = v[it].y;
                dst[2 * ESTRIDE] = v[it].z;
                dst[3 * ESTRIDE] = v[it].w;
            }
        }
        __syncthreads();
        cur ^= 1;
    }

    // lexicographic (value, index) merge across the 64 lanes of the wave
#pragma unroll
    for (int g = 0; g < 4; ++g)
#pragma unroll
        for (int i = 0; i < 4; ++i) {
            float vv = minv[g][i];
            int   ki = mini[g][i];
#pragma unroll
            for (int m = 1; m <= 32; m <<= 1) {
                float ov = __shfl_xor(vv, m, 64);
                int   oi = __shfl_xor(ki, m, 64);
                if (ov < vv || (ov == vv && oi < ki)) { vv = ov; ki = oi; }
            }
            if (lane == 0)
                out_idx[n0 + 16 * w + 4 * g + i] = (float)ki;
        }
}

// ---------------------------------------------------------------------------
// Histogram of final indices, for perplexity.
__global__ void hist_kernel(const float* __restrict__ idxf,
                            int* __restrict__ hist) {
    int n = blockIdx.x * 256 + threadIdx.x;
    atomicAdd(&hist[(int)idxf[n]], 1);
}

// ---------------------------------------------------------------------------
// Gather quantized vectors, write z_q_x, accumulate sum of squared errors.
__global__ void quantize_kernel(const float* __restrict__ z,
                                const float* __restrict__ emb,
                                const float* __restrict__ idxf,
                                float* __restrict__ zq,
                                float* __restrict__ sse) {
    int o = (blockIdx.x * 256 + threadIdx.x) * 4;
    int hw = o & 1023;
    int c  = (o >> 10) & 255;
    int b  = o >> 18;
    int nbase = b * 1024 + hw;
    float4 x = *(const float4*)(z + o);
    float q0 = emb[(size_t)((int)idxf[nbase + 0]) * D_EMB + c];
    float q1 = emb[(size_t)((int)idxf[nbase + 1]) * D_EMB + c];
    float q2 = emb[(size_t)((int)idxf[nbase + 2]) * D_EMB + c];
    float q3 = emb[(size_t)((int)idxf[nbase + 3]) * D_EMB + c];
    float4 q = make_float4(q0, q1, q2, q3);
    *(float4*)(zq + o) = q;
    float d0 = q.x - x.x, d1 = q.y - x.y, d2 = q.z - x.z, d3 = q.w - x.w;
    float s = d0 * d0 + d1 * d1 + d2 * d2 + d3 * d3;
#pragma unroll
    for (int m = 1; m < 64; m <<= 1) s += __shfl_xor(s, m, 64);
    __shared__ float red[4];
    int lane = threadIdx.x & 63, wv = threadIdx.x >> 6;
    if (lane == 0) red[wv] = s;
    __syncthreads();
    if (threadIdx.x == 0)
        atomicAdd(sse, red[0] + red[1] + red[2] + red[3]);
}

// ---------------------------------------------------------------------------
__global__ void finalize_kernel(const int* __restrict__ hist,
                                const float* __restrict__ sse,
                                float* __restrict__ out) {
    float s = 0.0f;
    for (int i = threadIdx.x; i < K_EMB; i += 256) {
        float p = (float)hist[i] * (1.0f / (float)NPIX);
        s += p * logf(p + 1e-10f);
    }
#pragma unroll
    for (int m = 1; m < 64; m <<= 1) s += __shfl_xor(s, m, 64);
    __shared__ float red[4];
    int lane = threadIdx.x & 63, wv = threadIdx.x >> 6;
    if (lane == 0) red[wv] = s;
    __syncthreads();
    if (threadIdx.x == 0) {
        float H = -(red[0] + red[1] + red[2] + red[3]);
        out[OUT_PERP] = expf(H);
        out[OUT_LOSS] = 1.25f * sse[0] / (float)NDTOT;
    }
}

// ---------------------------------------------------------------------------
extern "C" void kernel_launch(void* const* d_in, const int* in_sizes, int n_in,
                              void* d_out, int out_size, void* d_ws, size_t ws_size,
                              hipStream_t stream) {
    const float* z   = (const float*)d_in[0];   // [16,256,32,32]
    const float* emb = (const float*)d_in[1];   // [8192,256]
    float* out = (float*)d_out;
    char*  ws  = (char*)d_ws;
    float* sse  = (float*)(ws);
    int*   hist = (int*)(ws + WS_HIST_OFF);
    float* se2  = (float*)(ws + WS_SE2_OFF);
    float* sx2  = (float*)(ws + WS_SX2_OFF);

    // allow >64KB dynamic LDS (idempotent; capture-safe host call)
    static int attr_done = 0;
    if (!attr_done) {
        (void)hipFuncSetAttribute((const void*)argmin_kernel,
                                  hipFuncAttributeMaxDynamicSharedMemorySize,
                                  SMEM_BYTES);
        attr_done = 1;
    }

    // zero sse + hist every call (graph replays don't re-poison)
    hipMemsetAsync(d_ws, 0, WS_SE2_OFF, stream);

    sx2_kernel<<<NPIX / 256, 256, 0, stream>>>(z, sx2);
    se2_kernel<<<K_EMB / 256, 256, 0, stream>>>(emb, se2);
    argmin_kernel<<<NPIX / TN, 256, SMEM_BYTES, stream>>>(z, emb, se2, sx2,
                                                          out + OUT_IDX);
    hist_kernel<<<NPIX / 256, 256, 0, stream>>>(out + OUT_IDX, hist);
    quantize_kernel<<<NDTOT / (256 * 4), 256, 0, stream>>>(
        z, emb, out + OUT_IDX, out + OUT_ZQ, sse);
    finalize_kernel<<<1, 256, 0, stream>>>(hist, sse, out);
}